// Round 8
// baseline (8210.593 us; speedup 1.0000x reference)
//
#include <hip/hip_runtime.h>
#include <hip/hip_fp16.h>

#define LL 250
#define NBLK 256

typedef unsigned long long ull;

// ---- ws u32 offsets ----
#define WS_BAR    0        // 1024 (16 groups x 32)
#define WS_HG     1024     // [2][64 b][256] u32 fp16-pairs of h1
#define WS_H2G    33792    // [2][64 b][64] u32 fp16-pairs of h2
#define WS_WC     41984    // [4 ts][64 b][64 vp] u32 partial ctx
#define WS_WMS    58368    // [4][64][2] f32 (m,s)
#define WS_H2CTX  58880    // [64*250][256] f32
#define WS_INIT_END 58880

// ---- out scratch (float index units) ----
#define OUT_EMBW  0                 // 4096*2048 f32
#define OUT_EG    8388608           // EG2: 250*16*2048*2 u32
#define OUT_WP1   25165824          // 2048*320 u32
#define OUT_WP2   25821184          // 512*320 u32
#define OUT_KEYG  25985024          // 64*500*64 u32
#define OUT_VALG  28033024          // 64*128*250 u32

// ---- k_loop LDS byte offsets ----
#define L_KEY  0                    // [126][68] u32 = 34272
#define L_VAL  34272                // [128][68] u32 = 34816
#define L_X    69088                // [4][328] u32 = 5248
#define L_G    74336                // 512 f32
#define L_E    76384                // 128 f32
#define L_SPH  76896                // 64 u32
#define L_MS   77152                // 8 f32
#define L_H2S  77184                // 64 u32
#define L_B2   77440                // 32 f32
#define LDS_BYTES 77568

__device__ __forceinline__ float sigm(float x) { return 1.0f / (1.0f + __expf(-x)); }

__device__ __forceinline__ unsigned pk(float a, float b) {
    __half2 h;
    h.x = __float2half_rn(a); h.y = __float2half_rn(b);
    unsigned u; __builtin_memcpy(&u, &h, 4); return u;
}
__device__ __forceinline__ float2 upk(unsigned u) {
    __half2 h; __builtin_memcpy(&h, &u, 4);
    return make_float2(__half2float(h.x), __half2float(h.y));
}

// coherent (agent-scope, L2-bypassing) exchange accessors
__device__ __forceinline__ ull cld64(const ull* p) {
    return __hip_atomic_load(p, __ATOMIC_RELAXED, __HIP_MEMORY_SCOPE_AGENT);
}
__device__ __forceinline__ unsigned cld32(const unsigned* p) {
    return __hip_atomic_load(p, __ATOMIC_RELAXED, __HIP_MEMORY_SCOPE_AGENT);
}
__device__ __forceinline__ void cst64(ull* p, ull v) {
    __hip_atomic_store(p, v, __ATOMIC_RELAXED, __HIP_MEMORY_SCOPE_AGENT);
}
__device__ __forceinline__ void cst32(unsigned* p, unsigned v) {
    __hip_atomic_store(p, v, __ATOMIC_RELAXED, __HIP_MEMORY_SCOPE_AGENT);
}

#ifndef __has_builtin
#define __has_builtin(x) 0
#endif
#if __has_builtin(__builtin_amdgcn_fdot2)
typedef _Float16 h2vec __attribute__((ext_vector_type(2)));
__device__ __forceinline__ float dot2(unsigned a, unsigned b, float c) {
    h2vec ha, hb;
    __builtin_memcpy(&ha, &a, 4); __builtin_memcpy(&hb, &b, 4);
    return __builtin_amdgcn_fdot2(ha, hb, c, false);
}
#else
__device__ __forceinline__ float dot2(unsigned a, unsigned b, float c) {
    float2 fa = upk(a), fb = upk(b);
    return c + fa.x * fb.x + fa.y * fb.y;
}
#endif

// ---------------------------------------------------------------------------
__global__ __launch_bounds__(512) void k_init(const float* __restrict__ values,
                                              float* __restrict__ ws) {
    int i = blockIdx.x * 512 + threadIdx.x;
    if (i >= WS_INIT_END) return;
    unsigned* wsu = (unsigned*)ws;
    if (i >= WS_WC && i < WS_WC + 4096) {          // wc[0][bg][vp] = values[t=0]
        int r = i - WS_WC, bg = r >> 6, vp = r & 63;
        wsu[i] = pk(values[bg * 128 + 2 * vp], values[bg * 128 + 2 * vp + 1]);
    } else if (i >= WS_WMS) {
        int r = i - WS_WMS;                        // [4][64][2]: slice0 (m=0,s=1)
        ws[i] = (((r >> 7) == 0) && (r & 1)) ? 1.0f : 0.0f;
    } else {
        ws[i] = 0.0f;
    }
}

// ---------------------------------------------------------------------------
// pack weights/key/values to fp16 pairs
// ---------------------------------------------------------------------------
#define PK_W1 655360
#define PK_W2 819200
#define PK_KEY 2867200
#define PK_TOT 4915200
__global__ __launch_bounds__(512) void k_pack(
        const float* __restrict__ key, const float* __restrict__ values,
        const float* __restrict__ w_ih1, const float* __restrict__ w_hh1,
        const float* __restrict__ w_ih2, const float* __restrict__ w_hh2,
        unsigned* __restrict__ wp1, unsigned* __restrict__ wp2,
        unsigned* __restrict__ keyg, unsigned* __restrict__ valg) {
    int idx = blockIdx.x * 512 + threadIdx.x;
    if (idx >= PK_TOT) return;
    if (idx < PK_W1) {
        int j = idx / 320, kp = idx % 320, k0 = 2 * kp;
        float a, b;
        if (k0 < 128) { a = w_ih1[j * 384 + 256 + k0]; b = w_ih1[j * 384 + 257 + k0]; }
        else          { a = w_hh1[j * 512 + k0 - 128]; b = w_hh1[j * 512 + k0 - 127]; }
        wp1[idx] = pk(a, b);
    } else if (idx < PK_W2) {
        int i2 = idx - PK_W1;
        int j = i2 / 320, kp = i2 % 320, k0 = 2 * kp;
        float a, b;
        if (k0 < 512) { a = w_ih2[j * 512 + k0]; b = w_ih2[j * 512 + k0 + 1]; }
        else          { a = w_hh2[j * 128 + k0 - 512]; b = w_hh2[j * 128 + k0 - 511]; }
        wp2[i2] = pk(a, b);
    } else if (idx < PK_KEY) {
        int i2 = idx - PK_W2;
        int b = i2 / 32000, r = i2 % 32000, t = r >> 6, kp = r & 63;
        const float* kr = key + ((size_t)t * 64 + b) * 128 + 2 * kp;
        keyg[i2] = pk(kr[0], kr[1]);
    } else {
        int i2 = idx - PK_KEY;
        int b = i2 / 32000, r = i2 % 32000, tp = r >> 7, v = r & 127;
        valg[b * 32000 + v * 250 + tp] =
            pk(values[((size_t)(2 * tp) * 64 + b) * 128 + v],
               values[((size_t)(2 * tp + 1) * 64 + b) * 128 + v]);
    }
}

// ---------------------------------------------------------------------------
// EG2[l][g][j] = uint2{ pk(EmbW[tok(4g)][j],   pk for b pair 0/1),
//                       pk(EmbW[tok(4g+2)][j], b pair 2/3) }
// ---------------------------------------------------------------------------
__global__ __launch_bounds__(512) void k_eg2(const int* __restrict__ text,
                                             const float* __restrict__ EmbW,
                                             unsigned* __restrict__ EG2u) {
    const int jc = blockIdx.x, l = blockIdx.y;
    const int tid = threadIdx.x;
    __shared__ int tokL[64];
    if (tid < 64) tokL[tid] = (l == 0) ? 0 : text[tid * LL + l - 1];
    __syncthreads();
    const int j = jc * 256 + (tid & 255);
    const int half = tid >> 8;
    for (int gi = 0; gi < 8; ++gi) {
        int g = half * 8 + gi;
        float a0 = EmbW[(size_t)tokL[4 * g + 0] * 2048 + j];
        float a1 = EmbW[(size_t)tokL[4 * g + 1] * 2048 + j];
        float a2 = EmbW[(size_t)tokL[4 * g + 2] * 2048 + j];
        float a3 = EmbW[(size_t)tokL[4 * g + 3] * 2048 + j];
        uint2 u = make_uint2(pk(a0, a1), pk(a2, a3));
        *(uint2*)&EG2u[((size_t)(l * 16 + g) * 2048 + j) * 2] = u;
    }
}

// ---------------------------------------------------------------------------
// fp32 GEMM (K=256) — EmbW precompute and final projection
// ---------------------------------------------------------------------------
__global__ __launch_bounds__(256) void k_gemm_tn(
        const float* __restrict__ A, int lda,
        const float* __restrict__ B, int ldb,
        const float* __restrict__ bias1, const float* __restrict__ bias2,
        float* __restrict__ C, int ldc) {
    const int tid = threadIdx.x;
    const int m0 = blockIdx.y * 64, n0 = blockIdx.x * 64;
    const int tx = tid & 15, ty = tid >> 4;
    const int lm = tid >> 2, lk = (tid & 3) * 8;
    __shared__ float As[32][68];
    __shared__ float Bs[32][68];
    float c[4][4] = {{0.f}};
    for (int kb = 0; kb < 256; kb += 32) {
        const float* ap = A + (size_t)(m0 + lm) * lda + kb + lk;
        const float* bp = B + (size_t)(n0 + lm) * ldb + kb + lk;
        float4 a0 = *(const float4*)(ap);
        float4 a1 = *(const float4*)(ap + 4);
        float4 b0 = *(const float4*)(bp);
        float4 b1 = *(const float4*)(bp + 4);
        __syncthreads();
        As[lk + 0][lm] = a0.x; As[lk + 1][lm] = a0.y; As[lk + 2][lm] = a0.z; As[lk + 3][lm] = a0.w;
        As[lk + 4][lm] = a1.x; As[lk + 5][lm] = a1.y; As[lk + 6][lm] = a1.z; As[lk + 7][lm] = a1.w;
        Bs[lk + 0][lm] = b0.x; Bs[lk + 1][lm] = b0.y; Bs[lk + 2][lm] = b0.z; Bs[lk + 3][lm] = b0.w;
        Bs[lk + 4][lm] = b1.x; Bs[lk + 5][lm] = b1.y; Bs[lk + 6][lm] = b1.z; Bs[lk + 7][lm] = b1.w;
        __syncthreads();
#pragma unroll
        for (int kk = 0; kk < 32; ++kk) {
            const float4 a = *(const float4*)&As[kk][ty * 4];
            const float4 b = *(const float4*)&Bs[kk][tx * 4];
            c[0][0] += a.x * b.x; c[0][1] += a.x * b.y; c[0][2] += a.x * b.z; c[0][3] += a.x * b.w;
            c[1][0] += a.y * b.x; c[1][1] += a.y * b.y; c[1][2] += a.y * b.z; c[1][3] += a.y * b.w;
            c[2][0] += a.z * b.x; c[2][1] += a.z * b.y; c[2][2] += a.z * b.z; c[2][3] += a.z * b.w;
            c[3][0] += a.w * b.x; c[3][1] += a.w * b.y; c[3][2] += a.w * b.z; c[3][3] += a.w * b.w;
        }
    }
    const int n = n0 + tx * 4;
    float4 bb = *(const float4*)&bias1[n];
    if (bias2) {
        float4 b2 = *(const float4*)&bias2[n];
        bb.x += b2.x; bb.y += b2.y; bb.z += b2.z; bb.w += b2.w;
    }
#pragma unroll
    for (int i = 0; i < 4; ++i) {
        float4 r;
        r.x = c[i][0] + bb.x; r.y = c[i][1] + bb.y; r.z = c[i][2] + bb.z; r.w = c[i][3] + bb.w;
        *(float4*)&C[(size_t)(m0 + ty * 4 + i) * ldc + n] = r;
    }
}

// ---------------------------------------------------------------------------
// group sync split into arrive / wait so non-critical HBM writes can ride
// inside the barrier latency. Fence-free (all exchange is sc-coherent).
// ---------------------------------------------------------------------------
__device__ __forceinline__ void gb_arrive(unsigned* bar, int g, unsigned bk) {
    __syncthreads();   // drains vmcnt: all sc-stores visible at L3
    if (threadIdx.x == 0) {
        unsigned* cnt = bar + g * 32;
        unsigned a = __hip_atomic_fetch_add(cnt, 1u, __ATOMIC_RELAXED, __HIP_MEMORY_SCOPE_AGENT);
        if (a == bk * 16u - 1u)
            __hip_atomic_store(bar + g * 32 + 16, bk, __ATOMIC_RELAXED, __HIP_MEMORY_SCOPE_AGENT);
    }
}
__device__ __forceinline__ void gb_wait(unsigned* bar, int g, unsigned bk) {
    if (threadIdx.x == 0) {
        unsigned* gen = bar + g * 32 + 16;
        while (__hip_atomic_load(gen, __ATOMIC_RELAXED, __HIP_MEMORY_SCOPE_AGENT) < bk)
            __builtin_amdgcn_s_sleep(1);
    }
    __syncthreads();
}

// exact 4-slice merge: ctx-pair for (bgs, vp)
__device__ __forceinline__ void ctx_merge(const unsigned* __restrict__ wc32,
                                          const ull* __restrict__ wmsU,
                                          int bgs, int vp, float* cx, float* cy) {
    float m[4], sv[4];
#pragma unroll
    for (int q = 0; q < 4; ++q) {
        ull v = cld64(&wmsU[q * 64 + bgs]);
        float2 f; __builtin_memcpy(&f, &v, 8);
        m[q] = f.x; sv[q] = f.y;
    }
    float M = fmaxf(fmaxf(m[0], m[1]), fmaxf(m[2], m[3]));
    float w[4];
    float den = 0.f;
#pragma unroll
    for (int q = 0; q < 4; ++q) { w[q] = __expf(m[q] - M); den += w[q] * sv[q]; }
    float inv = 1.0f / den;
    float x = 0.f, y = 0.f;
#pragma unroll
    for (int q = 0; q < 4; ++q) {
        float2 f = upk(cld32(&wc32[q * 4096 + bgs * 64 + vp]));
        x += w[q] * f.x; y += w[q] * f.y;
    }
    *cx = x * inv; *cy = y * inv;
}

// ---------------------------------------------------------------------------
// Persistent kernel: 16 groups x 16 blocks; group owns 4 batch elems.
// S1: wave-uniform-b LSTM1 — h1 broadcast from VGPRs via v_readlane (no LDS),
//     ctx part from LDS; EG added post-loop (HBM latency hidden).
// S2: LSTM2 (32 rows x 4 b).  S3: attention slice.  3 split barriers/step.
// ---------------------------------------------------------------------------
__global__ __launch_bounds__(512) void k_loop(
        const int* __restrict__ speech_len,
        const unsigned* __restrict__ EG2u,
        const unsigned* __restrict__ wp1, const unsigned* __restrict__ wp2,
        const unsigned* __restrict__ keyg, const unsigned* __restrict__ valg,
        const float* __restrict__ b_ih2, const float* __restrict__ b_hh2,
        float* __restrict__ ws) {
    extern __shared__ char smem[];
    const int blk = blockIdx.x;
    const int tid = threadIdx.x;
    const int g = blk >> 4, s = blk & 15;

    unsigned* wsu = (unsigned*)ws;
    unsigned* bar   = wsu + WS_BAR;
    ull*      hgU   = (ull*)(wsu + WS_HG);     // [2][64][128]
    unsigned* hg32  = wsu + WS_HG;             // [2][64][256]
    ull*      h2gU  = (ull*)(wsu + WS_H2G);    // [2][64][32]
    unsigned* h2g32 = wsu + WS_H2G;            // [2][64][64]
    unsigned* wc32  = wsu + WS_WC;             // [4][64][64]
    ull*      wmsU  = (ull*)(wsu + WS_WMS);    // [4][64]
    float*    h2ctx = ws + WS_H2CTX;

    unsigned* keyL = (unsigned*)(smem + L_KEY);   // [126][68]
    unsigned* valL = (unsigned*)(smem + L_VAL);   // [128][68]
    unsigned* xL   = (unsigned*)(smem + L_X);     // [4][328]
    float*    gS   = (float*)(smem + L_G);        // [512]
    float*    eS   = (float*)(smem + L_E);        // [128]
    unsigned* sph  = (unsigned*)(smem + L_SPH);   // [64]
    float*    msS  = (float*)(smem + L_MS);       // [8]
    unsigned* h2S  = (unsigned*)(smem + L_H2S);   // [64]
    float*    b2S  = (float*)(smem + L_B2);       // [32]

    // attention slice geometry
    const int bl_att = s & 3, tsl = s >> 2;
    const int b_att = 4 * g + bl_att;
    const int pn  = (tsl < 2) ? 63 : 62;
    const int pp0 = (tsl < 2) ? 63 * tsl : 126 + 62 * (tsl - 2);
    const int t0 = 2 * pp0, tn = 2 * pn;

    // S1 wave geometry (wave-uniform b)
    const int wvi = tid >> 6, lane = tid & 63;
    const int wbl = wvi & 3, whalf = wvi >> 2;
    const int rl1 = whalf * 64 + lane;              // 0..127
    const int q1 = rl1 >> 5, hl1 = rl1 & 31;
    const int j1 = q1 * 512 + s * 32 + hl1;         // gate row

    // ---- prologue: key/val slices to LDS, lstm2 bias ----
    for (int i = tid; i < tn * 64; i += 512) {
        int tl = i >> 6, kp = i & 63;
        keyL[tl * 68 + kp] = keyg[(size_t)b_att * 32000 + (size_t)(t0 + tl) * 64 + kp];
    }
    for (int i = tid; i < 128 * 64; i += 512) {
        int v = i >> 6, pp = i & 63;
        valL[v * 68 + pp] = (pp < pn)
            ? valg[(size_t)b_att * 32000 + v * 250 + pp0 + pp] : 0u;
    }
    if (tid < 32) {
        int j2 = (tid >> 3) * 128 + s * 8 + (tid & 7);
        b2S[tid] = b_ih2[j2] + b_hh2[j2];
    }
    const int len_att = speech_len[b_att];
    __syncthreads();

    float c1 = 0.f, c2 = 0.f;
    unsigned bk = 0;

    for (int l = 0; l < LL; ++l) {
        const int cur = l & 1, nxt = cur ^ 1;
        float ctx_cx = 0.f, ctx_cy = 0.f;
        float h2_save = 0.f;

        // ================= S1: LSTM1 =================
        {
            // ctx merge into xL[bl][0..64) (LDS); keep values for tail write
            if (tid < 256) {
                int bl = tid & 3, vp = tid >> 2;
                ctx_merge(wc32, wmsU, 4 * g + bl, vp, &ctx_cx, &ctx_cy);
                xL[bl * 328 + vp] = pk(ctx_cx, ctx_cy);
            }
            // h1 into VGPRs (sc loads, wave-uniform b) + EG early
            const unsigned* hsrc = &hg32[cur * 16384 + (4 * g + wbl) * 256];
            unsigned xw0 = cld32(hsrc + 0 * 64 + lane);
            unsigned xw1 = cld32(hsrc + 1 * 64 + lane);
            unsigned xw2 = cld32(hsrc + 2 * 64 + lane);
            unsigned xw3 = cld32(hsrc + 3 * 64 + lane);
            float2 eg = upk(EG2u[((size_t)(l * 16 + g) * 2048 + j1) * 2 + (wbl >> 1)]);
            float egv = (wbl & 1) ? eg.y : eg.x;
            __syncthreads();   // xL (ctx) ready

            float acc0 = 0.f, acc1 = 0.f;
            const uint4* wpr = (const uint4*)(wp1 + (size_t)j1 * 320);
            const unsigned* xb = &xL[wbl * 328];
#pragma unroll
            for (int kk = 0; kk < 16; ++kk) {       // ctx part (LDS broadcast)
                uint4 wv = wpr[kk];
                uint4 xv = *(const uint4*)&xb[kk * 4];
                acc0 = dot2(wv.x, xv.x, acc0); acc1 = dot2(wv.y, xv.y, acc1);
                acc0 = dot2(wv.z, xv.z, acc0); acc1 = dot2(wv.w, xv.w, acc1);
            }
#define H1_BLOCK(XW, I0)                                                     \
            _Pragma("unroll")                                                \
            for (int i2 = 0; i2 < 16; ++i2) {                                \
                const int i = (I0) + i2;                                     \
                uint4 wv = wpr[16 + i];                                      \
                unsigned x0 = __builtin_amdgcn_readlane(XW, ((4*i) & 63));   \
                unsigned x1 = __builtin_amdgcn_readlane(XW, ((4*i) & 63)+1); \
                unsigned x2 = __builtin_amdgcn_readlane(XW, ((4*i) & 63)+2); \
                unsigned x3 = __builtin_amdgcn_readlane(XW, ((4*i) & 63)+3); \
                acc0 = dot2(wv.x, x0, acc0); acc1 = dot2(wv.y, x1, acc1);    \
                acc0 = dot2(wv.z, x2, acc0); acc1 = dot2(wv.w, x3, acc1);    \
            }
            H1_BLOCK(xw0, 0)
            H1_BLOCK(xw1, 16)
            H1_BLOCK(xw2, 32)
            H1_BLOCK(xw3, 48)
#undef H1_BLOCK
            gS[q1 * 128 + hl1 * 4 + wbl] = acc0 + acc1 + egv;
            __syncthreads();
            if (tid < 128) {
                int hl = tid >> 2, bl = tid & 3;
                float g0 = gS[tid], g1 = gS[128 + tid], g2 = gS[256 + tid], g3 = gS[384 + tid];
                float iv = sigm(g0), fv = sigm(g1), gv = tanhf(g2), ov = sigm(g3);
                c1 = fv * c1 + iv * gv;
                float h1v = ov * tanhf(c1);
                float hp = __shfl_xor(h1v, 4);
                if (!(hl & 1))
                    cst32(&hg32[nxt * 16384 + (4 * g + bl) * 256 + s * 16 + (hl >> 1)],
                          pk(h1v, hp));
            }
        }
        ++bk; gb_arrive(bar, g, bk);
        if (s == 0 && l > 0 && tid < 256) {       // tail: ctx row l-1 (epilogue-only)
            int bl = tid & 3, vp = tid >> 2;
            float* hd = &h2ctx[((size_t)(4 * g + bl) * LL + (l - 1)) * 256 + 128 + 2 * vp];
            hd[0] = ctx_cx; hd[1] = ctx_cy;
        }
        gb_wait(bar, g, bk);

        // ================= S2: LSTM2 =================
        {   // stage full h1 into xL[bl][0..256)
            int bl = tid >> 7, qp = tid & 127;
            ull d = cld64(&hgU[(size_t)nxt * 8192 + (4 * g + bl) * 128 + qp]);
            uint2 u; __builtin_memcpy(&u, &d, 8);
            *(uint2*)&xL[bl * 328 + 2 * qp] = u;
        }
        if (tid < 128) {  // h2 prev into xL[bl][256..320)
            int bl = tid >> 5, qp = tid & 31;
            ull d = cld64(&h2gU[(size_t)cur * 2048 + (4 * g + bl) * 32 + qp]);
            uint2 u; __builtin_memcpy(&u, &d, 8);
            *(uint2*)&xL[bl * 328 + 256 + 2 * qp] = u;
        }
        __syncthreads();
        {
            int job = tid >> 2, ks = tid & 3;
            int rl2 = job >> 2, bl = job & 3;
            int j2 = (rl2 >> 3) * 128 + s * 8 + (rl2 & 7);
            float acc = (ks == 0) ? b2S[rl2] : 0.f;
            const uint4* wpr = (const uint4*)(wp2 + (size_t)j2 * 320) + ks * 20;
            const unsigned* xb = &xL[bl * 328 + ks * 80];
#pragma unroll 5
            for (int it = 0; it < 20; ++it) {
                uint4 wv = wpr[it];
                uint4 xv = *(const uint4*)&xb[it * 4];
                acc = dot2(wv.x, xv.x, acc); acc = dot2(wv.y, xv.y, acc);
                acc = dot2(wv.z, xv.z, acc); acc = dot2(wv.w, xv.w, acc);
            }
            acc += __shfl_xor(acc, 1);
            acc += __shfl_xor(acc, 2);
            if (ks == 0) gS[job] = acc;
        }
        __syncthreads();
        if (tid < 32) {
            int rl = tid >> 2, bl = tid & 3;
            float g0 = gS[tid], g1 = gS[32 + tid], g2 = gS[64 + tid], g3 = gS[96 + tid];
            float iv = sigm(g0), fv = sigm(g1), gv = tanhf(g2), ov = sigm(g3);
            c2 = fv * c2 + iv * gv;
            float h2v = ov * tanhf(c2);
            h2_save = h2v;
            float hp = __shfl_xor(h2v, 4);
            if (!(rl & 1))
                cst32(&h2g32[nxt * 4096 + (4 * g + bl) * 64 + s * 4 + (rl >> 1)],
                      pk(h2v, hp));
        }
        ++bk; gb_arrive(bar, g, bk);
        if (tid < 32) {                            // tail: h2ctx row (epilogue-only)
            int rl = tid >> 2, bl = tid & 3;
            h2ctx[((size_t)(4 * g + bl) * LL + l) * 256 + s * 8 + rl] = h2_save;
        }
        gb_wait(bar, g, bk);

        // ================= S3: attention slice =================
        if (tid < 32) {
            ull d = cld64(&h2gU[(size_t)nxt * 2048 + b_att * 32 + tid]);
            uint2 u; __builtin_memcpy(&u, &d, 8);
            *(uint2*)&h2S[2 * tid] = u;
        }
        __syncthreads();
        {   // energies
            int tl = tid >> 2, ks = tid & 3;
            float e = 0.f;
            if (tl < tn) {
                const uint4* kr = (const uint4*)&keyL[tl * 68] + ks * 4;
                const uint4* hr = (const uint4*)&h2S[ks * 16];
#pragma unroll
                for (int it = 0; it < 4; ++it) {
                    uint4 kv = kr[it]; uint4 hv = hr[it];
                    e = dot2(kv.x, hv.x, e); e = dot2(kv.y, hv.y, e);
                    e = dot2(kv.z, hv.z, e); e = dot2(kv.w, hv.w, e);
                }
            }
            e += __shfl_xor(e, 1);
            e += __shfl_xor(e, 2);
            if (ks == 0 && tl < tn)
                eS[tl] = (t0 + tl < len_att) ? e : 0.0f;
        }
        __syncthreads();
        float att_m = 0.f, att_s = 0.f;
        {
            float me = -1e30f, p = 0.f;
            if (tid < 128) {
                me = (tid < tn) ? eS[tid] : -1e30f;
                float mv = me;
#pragma unroll
                for (int off = 32; off; off >>= 1) mv = fmaxf(mv, __shfl_xor(mv, off));
                if ((tid & 63) == 0) msS[tid >> 6] = mv;
            }
            __syncthreads();
            float m = fmaxf(msS[0], msS[1]);
            if (tid < 128) {
                p = (tid < tn) ? __expf(me - m) : 0.0f;
                float sv = p;
#pragma unroll
                for (int off = 32; off; off >>= 1) sv += __shfl_xor(sv, off);
                if ((tid & 63) == 0) msS[2 + (tid >> 6)] = sv;
                float pnb = __shfl_xor(p, 1);
                if (!(tid & 1)) sph[tid >> 1] = pk(p, pnb);
            }
            __syncthreads();
            att_m = m;
            att_s = msS[2] + msS[3];
        }
        {   // partial context
            int v = tid >> 2, th = tid & 3;
            float a = 0.f;
            const uint4* vr = (const uint4*)&valL[v * 68] + th * 4;
            const uint4* pr = (const uint4*)&sph[th * 16];
#pragma unroll
            for (int it = 0; it < 4; ++it) {
                uint4 vv = vr[it]; uint4 pv = pr[it];
                a = dot2(vv.x, pv.x, a); a = dot2(vv.y, pv.y, a);
                a = dot2(vv.z, pv.z, a); a = dot2(vv.w, pv.w, a);
            }
            a += __shfl_xor(a, 1);
            a += __shfl_xor(a, 2);
            float an = __shfl_xor(a, 4);
            if (th == 0 && !(v & 1))
                cst32(&wc32[tsl * 4096 + b_att * 64 + (v >> 1)], pk(a, an));
            if (tid == 0) {
                float2 msf = make_float2(att_m, att_s);
                ull v64; __builtin_memcpy(&v64, &msf, 8);
                cst64(&wmsU[tsl * 64 + b_att], v64);
            }
        }
        ++bk; gb_arrive(bar, g, bk);
        gb_wait(bar, g, bk);
    }

    // tail: ctx rows for l = 249
    if (s == 0 && tid < 256) {
        int bl = tid & 3, vp = tid >> 2;
        float cx, cy;
        ctx_merge(wc32, wmsU, 4 * g + bl, vp, &cx, &cy);
        float* hd = &h2ctx[((size_t)(4 * g + bl) * LL + (LL - 1)) * 256 + 128 + 2 * vp];
        hd[0] = cx; hd[1] = cy;
    }
}

// ---------------------------------------------------------------------------
extern "C" void kernel_launch(void* const* d_in, const int* in_sizes, int n_in,
                              void* d_out, int out_size, void* d_ws, size_t ws_size,
                              hipStream_t stream) {
    const float* key        = (const float*)d_in[0];
    const float* values     = (const float*)d_in[1];
    const int*   speech_len = (const int*)d_in[2];
    const int*   text       = (const int*)d_in[3];
    const float* embedding  = (const float*)d_in[4];
    const float* w_ih1 = (const float*)d_in[5];
    const float* b_ih1 = (const float*)d_in[6];
    const float* w_hh1 = (const float*)d_in[7];
    const float* b_hh1 = (const float*)d_in[8];
    const float* w_ih2 = (const float*)d_in[9];
    const float* b_ih2 = (const float*)d_in[10];
    const float* w_hh2 = (const float*)d_in[11];
    const float* b_hh2 = (const float*)d_in[12];
    const float* w_out = (const float*)d_in[13];
    const float* b_out = (const float*)d_in[14];
    float* out = (float*)d_out;

    float* ws    = (float*)d_ws;
    float* h2ctx = ws + WS_H2CTX;

    float* EmbW = out + OUT_EMBW;
    unsigned* EG2u = (unsigned*)(out + OUT_EG);
    unsigned* wp1  = (unsigned*)(out + OUT_WP1);
    unsigned* wp2  = (unsigned*)(out + OUT_WP2);
    unsigned* keyg = (unsigned*)(out + OUT_KEYG);
    unsigned* valg = (unsigned*)(out + OUT_VALG);

    (void)hipFuncSetAttribute((const void*)k_loop,
                              hipFuncAttributeMaxDynamicSharedMemorySize, LDS_BYTES);

    k_init<<<115, 512, 0, stream>>>(values, ws);
    k_pack<<<(PK_TOT + 511) / 512, 512, 0, stream>>>(key, values, w_ih1, w_hh1,
                                                     w_ih2, w_hh2, wp1, wp2, keyg, valg);
    // EmbW[v][j] = embedding[v] . w_ih1[j][:256] + b_ih1[j] + b_hh1[j]
    k_gemm_tn<<<dim3(32, 64), 256, 0, stream>>>(embedding, 256, w_ih1, 384,
                                                b_ih1, b_hh1, EmbW, 2048);
    k_eg2<<<dim3(8, 250), 512, 0, stream>>>(text, EmbW, EG2u);
    k_loop<<<NBLK, 512, LDS_BYTES, stream>>>(speech_len, EG2u, wp1, wp2, keyg, valg,
                                             b_ih2, b_hh2, ws);
    // out[b*250+l][v] = h2ctx[b*250+l] . w_out[v] + b_out[v]
    k_gemm_tn<<<dim3(64, 250), 256, 0, stream>>>(h2ctx, 256, w_out, 256,
                                                 b_out, nullptr, out, 4096);
}

// Round 10
// 4700.662 us; speedup vs baseline: 1.7467x; 1.7467x over previous
//
#include <hip/hip_runtime.h>
#include <hip/hip_fp16.h>

#define LL 250
#define NBLK 256

typedef unsigned long long ull;

// ---- ws u32 offsets ----
#define WS_BAR    0        // 16 groups x 32 u32: cnt @ +0, gen @ +16 (monotonic)
#define WS_HG     1024     // [2][64 b][256] u32 fp16-pairs of h1
#define WS_H2G    33792    // [2][64 b][64] u32 fp16-pairs of h2
#define WS_WC     41984    // [4 ts][64 b][64 vp] u32 partial ctx
#define WS_WMS    58368    // [4][64][2] f32 (m,s)
#define WS_H2CTX  58880    // [64*250][256] f32
#define WS_INIT_END 58880

// ---- out scratch (float index units) ----
#define OUT_EMBW  0                 // 4096*2048 f32
#define OUT_EG    8388608           // EG2: 250*16*2048*2 u32
#define OUT_WP1   25165824          // 2048*320 u32
#define OUT_WP2   25821184          // 512*320 u32
#define OUT_KEYG  25985024          // 64*500*64 u32
#define OUT_VALG  28033024          // 64*128*250 u32

// ---- k_loop LDS byte offsets ----
#define L_KEY  0                    // [126][68] u32 = 34272
#define L_VAL  34272                // [128][68] u32 = 34816
#define L_X    69088                // [4][328] u32 = 5248
#define L_G    74336                // 512 f32
#define L_E    76384                // 128 f32
#define L_SPH  76896                // 64 u32
#define L_MS   77152                // 8 f32
#define L_H2S  77184                // 64 u32
#define L_B2   77440                // 32 f32
#define LDS_BYTES 77568

__device__ __forceinline__ float sigm(float x) { return 1.0f / (1.0f + __expf(-x)); }

__device__ __forceinline__ unsigned pk(float a, float b) {
    __half2 h;
    h.x = __float2half_rn(a); h.y = __float2half_rn(b);
    unsigned u; __builtin_memcpy(&u, &h, 4); return u;
}
__device__ __forceinline__ float2 upk(unsigned u) {
    __half2 h; __builtin_memcpy(&h, &u, 4);
    return make_float2(__half2float(h.x), __half2float(h.y));
}

// coherent (agent-scope, L2-bypassing) exchange accessors
__device__ __forceinline__ ull cld64(const ull* p) {
    return __hip_atomic_load(p, __ATOMIC_RELAXED, __HIP_MEMORY_SCOPE_AGENT);
}
__device__ __forceinline__ unsigned cld32(const unsigned* p) {
    return __hip_atomic_load(p, __ATOMIC_RELAXED, __HIP_MEMORY_SCOPE_AGENT);
}
__device__ __forceinline__ void cst64(ull* p, ull v) {
    __hip_atomic_store(p, v, __ATOMIC_RELAXED, __HIP_MEMORY_SCOPE_AGENT);
}
__device__ __forceinline__ void cst32(unsigned* p, unsigned v) {
    __hip_atomic_store(p, v, __ATOMIC_RELAXED, __HIP_MEMORY_SCOPE_AGENT);
}

#ifndef __has_builtin
#define __has_builtin(x) 0
#endif
#if __has_builtin(__builtin_amdgcn_fdot2)
typedef _Float16 h2vec __attribute__((ext_vector_type(2)));
__device__ __forceinline__ float dot2(unsigned a, unsigned b, float c) {
    h2vec ha, hb;
    __builtin_memcpy(&ha, &a, 4); __builtin_memcpy(&hb, &b, 4);
    return __builtin_amdgcn_fdot2(ha, hb, c, false);
}
#else
__device__ __forceinline__ float dot2(unsigned a, unsigned b, float c) {
    float2 fa = upk(a), fb = upk(b);
    return c + fa.x * fb.x + fa.y * fb.y;
}
#endif

// ---------------------------------------------------------------------------
__global__ __launch_bounds__(512) void k_init(const float* __restrict__ values,
                                              float* __restrict__ ws) {
    int i = blockIdx.x * 512 + threadIdx.x;
    if (i >= WS_INIT_END) return;
    unsigned* wsu = (unsigned*)ws;
    if (i >= WS_WC && i < WS_WC + 4096) {          // wc[0][bg][vp] = values[t=0]
        int r = i - WS_WC, bg = r >> 6, vp = r & 63;
        wsu[i] = pk(values[bg * 128 + 2 * vp], values[bg * 128 + 2 * vp + 1]);
    } else if (i >= WS_WMS) {
        int r = i - WS_WMS;                        // [4][64][2]: slice0 (m=0,s=1)
        ws[i] = (((r >> 7) == 0) && (r & 1)) ? 1.0f : 0.0f;
    } else {
        ws[i] = 0.0f;
    }
}

// ---------------------------------------------------------------------------
// pack weights/key/values to fp16 pairs
// ---------------------------------------------------------------------------
#define PK_W1 655360
#define PK_W2 819200
#define PK_KEY 2867200
#define PK_TOT 4915200
__global__ __launch_bounds__(512) void k_pack(
        const float* __restrict__ key, const float* __restrict__ values,
        const float* __restrict__ w_ih1, const float* __restrict__ w_hh1,
        const float* __restrict__ w_ih2, const float* __restrict__ w_hh2,
        unsigned* __restrict__ wp1, unsigned* __restrict__ wp2,
        unsigned* __restrict__ keyg, unsigned* __restrict__ valg) {
    int idx = blockIdx.x * 512 + threadIdx.x;
    if (idx >= PK_TOT) return;
    if (idx < PK_W1) {
        int j = idx / 320, kp = idx % 320, k0 = 2 * kp;
        float a, b;
        if (k0 < 128) { a = w_ih1[j * 384 + 256 + k0]; b = w_ih1[j * 384 + 257 + k0]; }
        else          { a = w_hh1[j * 512 + k0 - 128]; b = w_hh1[j * 512 + k0 - 127]; }
        wp1[idx] = pk(a, b);
    } else if (idx < PK_W2) {
        int i2 = idx - PK_W1;
        int j = i2 / 320, kp = i2 % 320, k0 = 2 * kp;
        float a, b;
        if (k0 < 512) { a = w_ih2[j * 512 + k0]; b = w_ih2[j * 512 + k0 + 1]; }
        else          { a = w_hh2[j * 128 + k0 - 512]; b = w_hh2[j * 128 + k0 - 511]; }
        wp2[i2] = pk(a, b);
    } else if (idx < PK_KEY) {
        int i2 = idx - PK_W2;
        int b = i2 / 32000, r = i2 % 32000, t = r >> 6, kp = r & 63;
        const float* kr = key + ((size_t)t * 64 + b) * 128 + 2 * kp;
        keyg[i2] = pk(kr[0], kr[1]);
    } else {
        int i2 = idx - PK_KEY;
        int b = i2 / 32000, r = i2 % 32000, tp = r >> 7, v = r & 127;
        valg[b * 32000 + v * 250 + tp] =
            pk(values[((size_t)(2 * tp) * 64 + b) * 128 + v],
               values[((size_t)(2 * tp + 1) * 64 + b) * 128 + v]);
    }
}

// ---------------------------------------------------------------------------
// EG2[l][g][j] = uint2{ pk(b0,b1), pk(b2,b3) } of EmbW[tok][j]
// ---------------------------------------------------------------------------
__global__ __launch_bounds__(512) void k_eg2(const int* __restrict__ text,
                                             const float* __restrict__ EmbW,
                                             unsigned* __restrict__ EG2u) {
    const int jc = blockIdx.x, l = blockIdx.y;
    const int tid = threadIdx.x;
    __shared__ int tokL[64];
    if (tid < 64) tokL[tid] = (l == 0) ? 0 : text[tid * LL + l - 1];
    __syncthreads();
    const int j = jc * 256 + (tid & 255);
    const int half = tid >> 8;
    for (int gi = 0; gi < 8; ++gi) {
        int g = half * 8 + gi;
        float a0 = EmbW[(size_t)tokL[4 * g + 0] * 2048 + j];
        float a1 = EmbW[(size_t)tokL[4 * g + 1] * 2048 + j];
        float a2 = EmbW[(size_t)tokL[4 * g + 2] * 2048 + j];
        float a3 = EmbW[(size_t)tokL[4 * g + 3] * 2048 + j];
        uint2 u = make_uint2(pk(a0, a1), pk(a2, a3));
        *(uint2*)&EG2u[((size_t)(l * 16 + g) * 2048 + j) * 2] = u;
    }
}

// ---------------------------------------------------------------------------
// fp32 GEMM (K=256) — EmbW precompute and final projection
// ---------------------------------------------------------------------------
__global__ __launch_bounds__(256) void k_gemm_tn(
        const float* __restrict__ A, int lda,
        const float* __restrict__ B, int ldb,
        const float* __restrict__ bias1, const float* __restrict__ bias2,
        float* __restrict__ C, int ldc) {
    const int tid = threadIdx.x;
    const int m0 = blockIdx.y * 64, n0 = blockIdx.x * 64;
    const int tx = tid & 15, ty = tid >> 4;
    const int lm = tid >> 2, lk = (tid & 3) * 8;
    __shared__ float As[32][68];
    __shared__ float Bs[32][68];
    float c[4][4] = {{0.f}};
    for (int kb = 0; kb < 256; kb += 32) {
        const float* ap = A + (size_t)(m0 + lm) * lda + kb + lk;
        const float* bp = B + (size_t)(n0 + lm) * ldb + kb + lk;
        float4 a0 = *(const float4*)(ap);
        float4 a1 = *(const float4*)(ap + 4);
        float4 b0 = *(const float4*)(bp);
        float4 b1 = *(const float4*)(bp + 4);
        __syncthreads();
        As[lk + 0][lm] = a0.x; As[lk + 1][lm] = a0.y; As[lk + 2][lm] = a0.z; As[lk + 3][lm] = a0.w;
        As[lk + 4][lm] = a1.x; As[lk + 5][lm] = a1.y; As[lk + 6][lm] = a1.z; As[lk + 7][lm] = a1.w;
        Bs[lk + 0][lm] = b0.x; Bs[lk + 1][lm] = b0.y; Bs[lk + 2][lm] = b0.z; Bs[lk + 3][lm] = b0.w;
        Bs[lk + 4][lm] = b1.x; Bs[lk + 5][lm] = b1.y; Bs[lk + 6][lm] = b1.z; Bs[lk + 7][lm] = b1.w;
        __syncthreads();
#pragma unroll
        for (int kk = 0; kk < 32; ++kk) {
            const float4 a = *(const float4*)&As[kk][ty * 4];
            const float4 b = *(const float4*)&Bs[kk][tx * 4];
            c[0][0] += a.x * b.x; c[0][1] += a.x * b.y; c[0][2] += a.x * b.z; c[0][3] += a.x * b.w;
            c[1][0] += a.y * b.x; c[1][1] += a.y * b.y; c[1][2] += a.y * b.z; c[1][3] += a.y * b.w;
            c[2][0] += a.z * b.x; c[2][1] += a.z * b.y; c[2][2] += a.z * b.z; c[2][3] += a.z * b.w;
            c[3][0] += a.w * b.x; c[3][1] += a.w * b.y; c[3][2] += a.w * b.z; c[3][3] += a.w * b.w;
        }
    }
    const int n = n0 + tx * 4;
    float4 bb = *(const float4*)&bias1[n];
    if (bias2) {
        float4 b2 = *(const float4*)&bias2[n];
        bb.x += b2.x; bb.y += b2.y; bb.z += b2.z; bb.w += b2.w;
    }
#pragma unroll
    for (int i = 0; i < 4; ++i) {
        float4 r;
        r.x = c[i][0] + bb.x; r.y = c[i][1] + bb.y; r.z = c[i][2] + bb.z; r.w = c[i][3] + bb.w;
        *(float4*)&C[(size_t)(m0 + ty * 4 + i) * ldc + n] = r;
    }
}

// ---------------------------------------------------------------------------
// Counter-based group sync (R7/R8-proven under graph replay), split into
// arrive / wait so epilogue-only HBM writes ride inside the sync window.
// Monotonic cnt/gen; relaxed atomics; __syncthreads drains vmcnt pre-arrive.
// ---------------------------------------------------------------------------
__device__ __forceinline__ void gb_arrive(unsigned* bar, int g, unsigned bk) {
    __syncthreads();
    if (threadIdx.x == 0) {
        unsigned* cnt = bar + g * 32;
        unsigned a = __hip_atomic_fetch_add(cnt, 1u, __ATOMIC_RELAXED, __HIP_MEMORY_SCOPE_AGENT);
        if (a == bk * 16u - 1u)
            __hip_atomic_store(bar + g * 32 + 16, bk, __ATOMIC_RELAXED, __HIP_MEMORY_SCOPE_AGENT);
    }
}
__device__ __forceinline__ void gb_wait(unsigned* bar, int g, unsigned bk) {
    if (threadIdx.x == 0) {
        unsigned* gen = bar + g * 32 + 16;
        while (__hip_atomic_load(gen, __ATOMIC_RELAXED, __HIP_MEMORY_SCOPE_AGENT) < bk)
            __builtin_amdgcn_s_sleep(1);
    }
    __syncthreads();
}

// exact 4-slice merge: ctx-pair for (bgs, vp)
__device__ __forceinline__ void ctx_merge(const unsigned* __restrict__ wc32,
                                          const ull* __restrict__ wmsU,
                                          int bgs, int vp, float* cx, float* cy) {
    float m[4], sv[4];
#pragma unroll
    for (int q = 0; q < 4; ++q) {
        ull v = cld64(&wmsU[q * 64 + bgs]);
        float2 f; __builtin_memcpy(&f, &v, 8);
        m[q] = f.x; sv[q] = f.y;
    }
    float M = fmaxf(fmaxf(m[0], m[1]), fmaxf(m[2], m[3]));
    float w[4];
    float den = 0.f;
#pragma unroll
    for (int q = 0; q < 4; ++q) { w[q] = __expf(m[q] - M); den += w[q] * sv[q]; }
    float inv = 1.0f / den;
    float x = 0.f, y = 0.f;
#pragma unroll
    for (int q = 0; q < 4; ++q) {
        float2 f = upk(cld32(&wc32[q * 4096 + bgs * 64 + vp]));
        x += w[q] * f.x; y += w[q] * f.y;
    }
    *cx = x * inv; *cy = y * inv;
}

// ---------------------------------------------------------------------------
// Persistent kernel: 16 groups x 16 blocks; group owns 4 batch elems.
// S1 LSTM1 (128 rows x 4 b, line-cooperative wp1 stream) | sync |
// S2 LSTM2 (32 rows x 4 b) | sync | S3 attention slice | sync.
// Epilogue-only h2ctx writes ride inside the arrive/wait windows.
// ---------------------------------------------------------------------------
__global__ __launch_bounds__(512) void k_loop(
        const int* __restrict__ speech_len,
        const unsigned* __restrict__ EG2u,
        const unsigned* __restrict__ wp1, const unsigned* __restrict__ wp2,
        const unsigned* __restrict__ keyg, const unsigned* __restrict__ valg,
        const float* __restrict__ b_ih2, const float* __restrict__ b_hh2,
        float* __restrict__ ws) {
    extern __shared__ char smem[];
    const int blk = blockIdx.x;
    const int tid = threadIdx.x;
    const int g = blk >> 4, s = blk & 15;

    unsigned* wsu = (unsigned*)ws;
    unsigned* bar   = wsu + WS_BAR;
    ull*      hgU   = (ull*)(wsu + WS_HG);     // [2][64][128]
    unsigned* hg32  = wsu + WS_HG;             // [2][64][256]
    ull*      h2gU  = (ull*)(wsu + WS_H2G);    // [2][64][32]
    unsigned* h2g32 = wsu + WS_H2G;            // [2][64][64]
    unsigned* wc32  = wsu + WS_WC;             // [4][64][64]
    ull*      wmsU  = (ull*)(wsu + WS_WMS);    // [4][64]
    float*    h2ctx = ws + WS_H2CTX;

    unsigned* keyL = (unsigned*)(smem + L_KEY);   // [126][68]
    unsigned* valL = (unsigned*)(smem + L_VAL);   // [128][68]
    unsigned* xL   = (unsigned*)(smem + L_X);     // [4][328]
    float*    gS   = (float*)(smem + L_G);        // [512]
    float*    eS   = (float*)(smem + L_E);        // [128]
    unsigned* sph  = (unsigned*)(smem + L_SPH);   // [64]
    float*    msS  = (float*)(smem + L_MS);       // [8]
    unsigned* h2S  = (unsigned*)(smem + L_H2S);   // [64]
    float*    b2S  = (float*)(smem + L_B2);       // [32]

    // attention slice geometry
    const int bl_att = s & 3, tsl = s >> 2;
    const int b_att = 4 * g + bl_att;
    const int pn  = (tsl < 2) ? 63 : 62;
    const int pp0 = (tsl < 2) ? 63 * tsl : 126 + 62 * (tsl - 2);
    const int t0 = 2 * pp0, tn = 2 * pn;

    // ---- prologue: key/val slices to LDS, lstm2 bias ----
    for (int i = tid; i < tn * 64; i += 512) {
        int tl = i >> 6, kp = i & 63;
        keyL[tl * 68 + kp] = keyg[(size_t)b_att * 32000 + (size_t)(t0 + tl) * 64 + kp];
    }
    for (int i = tid; i < 128 * 64; i += 512) {
        int v = i >> 6, pp = i & 63;
        valL[v * 68 + pp] = (pp < pn)
            ? valg[(size_t)b_att * 32000 + v * 250 + pp0 + pp] : 0u;
    }
    if (tid < 32) {
        int j2 = (tid >> 3) * 128 + s * 8 + (tid & 7);
        b2S[tid] = b_ih2[j2] + b_hh2[j2];
    }
    const int len_att = speech_len[b_att];
    __syncthreads();

    float c1 = 0.f, c2 = 0.f;
    unsigned bk = 0;

    for (int l = 0; l < LL; ++l) {
        const int cur = l & 1, nxt = cur ^ 1;
        float ctx_cx = 0.f, ctx_cy = 0.f;
        float h2_save = 0.f;

        // ================= S1: LSTM1 =================
        {   // stage h1(prev) into xL[bl][64..320)
            int bl = tid >> 7, qp = tid & 127;
            ull d = cld64(&hgU[(size_t)cur * 8192 + (4 * g + bl) * 128 + qp]);
            uint2 u; __builtin_memcpy(&u, &d, 8);
            *(uint2*)&xL[bl * 328 + 64 + 2 * qp] = u;
        }
        if (tid < 256) {  // ctx merge into xL[bl][0..64); keep for tail write
            int bl = tid & 3, vp = tid >> 2;
            ctx_merge(wc32, wmsU, 4 * g + bl, vp, &ctx_cx, &ctx_cy);
            xL[bl * 328 + vp] = pk(ctx_cx, ctx_cy);
        }
        __syncthreads();
        {   // gates: thread = (row_local rl, bl); EG off the chain; 2 acc chains
            int rl = tid >> 2, bl = tid & 3;
            int q = rl >> 5, hl = rl & 31;
            int j = q * 512 + s * 32 + hl;
            float2 eg = upk(EG2u[((size_t)(l * 16 + g) * 2048 + j) * 2 + (bl >> 1)]);
            float egv = (bl & 1) ? eg.y : eg.x;
            float acc0 = 0.f, acc1 = 0.f;
            const uint4* wp = (const uint4*)(wp1 + (size_t)j * 320);
            const unsigned* xb = &xL[bl * 328];
#pragma unroll 8
            for (int it = 0; it < 80; ++it) {
                uint4 wv = wp[it];
                uint4 xv = *(const uint4*)&xb[it * 4];
                acc0 = dot2(wv.x, xv.x, acc0); acc1 = dot2(wv.y, xv.y, acc1);
                acc0 = dot2(wv.z, xv.z, acc0); acc1 = dot2(wv.w, xv.w, acc1);
            }
            gS[tid] = acc0 + acc1 + egv;
        }
        __syncthreads();
        if (tid < 128) {
            int hl = tid >> 2, bl = tid & 3;
            float g0 = gS[tid], g1 = gS[128 + tid], g2 = gS[256 + tid], g3 = gS[384 + tid];
            float iv = sigm(g0), fv = sigm(g1), gv = tanhf(g2), ov = sigm(g3);
            c1 = fv * c1 + iv * gv;
            float h1v = ov * tanhf(c1);
            float hp = __shfl_xor(h1v, 4);
            if (!(hl & 1))
                cst32(&hg32[nxt * 16384 + (4 * g + bl) * 256 + s * 16 + (hl >> 1)],
                      pk(h1v, hp));
        }
        ++bk; gb_arrive(bar, g, bk);
        if (s == 0 && l > 0 && tid < 256) {     // epilogue-only: ctx row l-1
            int bl = tid & 3, vp = tid >> 2;
            float* hd = &h2ctx[((size_t)(4 * g + bl) * LL + (l - 1)) * 256 + 128 + 2 * vp];
            hd[0] = ctx_cx; hd[1] = ctx_cy;
        }
        gb_wait(bar, g, bk);

        // ================= S2: LSTM2 =================
        {   // stage full h1 into xL[bl][0..256)
            int bl = tid >> 7, qp = tid & 127;
            ull d = cld64(&hgU[(size_t)nxt * 8192 + (4 * g + bl) * 128 + qp]);
            uint2 u; __builtin_memcpy(&u, &d, 8);
            *(uint2*)&xL[bl * 328 + 2 * qp] = u;
        }
        if (tid < 128) {  // h2 prev into xL[bl][256..320)
            int bl = tid >> 5, qp = tid & 31;
            ull d = cld64(&h2gU[(size_t)cur * 2048 + (4 * g + bl) * 32 + qp]);
            uint2 u; __builtin_memcpy(&u, &d, 8);
            *(uint2*)&xL[bl * 328 + 256 + 2 * qp] = u;
        }
        __syncthreads();
        {
            int job = tid >> 2, ks = tid & 3;
            int rl2 = job >> 2, bl = job & 3;
            int j2 = (rl2 >> 3) * 128 + s * 8 + (rl2 & 7);
            float acc0 = (ks == 0) ? b2S[rl2] : 0.f;
            float acc1 = 0.f;
            const uint4* wp = (const uint4*)(wp2 + (size_t)j2 * 320) + ks * 20;
            const unsigned* xb = &xL[bl * 328 + ks * 80];
#pragma unroll 5
            for (int it = 0; it < 20; ++it) {
                uint4 wv = wp[it];
                uint4 xv = *(const uint4*)&xb[it * 4];
                acc0 = dot2(wv.x, xv.x, acc0); acc1 = dot2(wv.y, xv.y, acc1);
                acc0 = dot2(wv.z, xv.z, acc0); acc1 = dot2(wv.w, xv.w, acc1);
            }
            float acc = acc0 + acc1;
            acc += __shfl_xor(acc, 1);
            acc += __shfl_xor(acc, 2);
            if (ks == 0) gS[job] = acc;
        }
        __syncthreads();
        if (tid < 32) {
            int rl = tid >> 2, bl = tid & 3;
            float g0 = gS[tid], g1 = gS[32 + tid], g2 = gS[64 + tid], g3 = gS[96 + tid];
            float iv = sigm(g0), fv = sigm(g1), gv = tanhf(g2), ov = sigm(g3);
            c2 = fv * c2 + iv * gv;
            float h2v = ov * tanhf(c2);
            h2_save = h2v;
            float hp = __shfl_xor(h2v, 4);
            if (!(rl & 1))
                cst32(&h2g32[nxt * 4096 + (4 * g + bl) * 64 + s * 4 + (rl >> 1)],
                      pk(h2v, hp));
        }
        ++bk; gb_arrive(bar, g, bk);
        if (tid < 32) {                          // epilogue-only: h2ctx h2 row
            int rl = tid >> 2, bl = tid & 3;
            h2ctx[((size_t)(4 * g + bl) * LL + l) * 256 + s * 8 + rl] = h2_save;
        }
        gb_wait(bar, g, bk);

        // ================= S3: attention slice =================
        if (tid < 32) {
            ull d = cld64(&h2gU[(size_t)nxt * 2048 + b_att * 32 + tid]);
            uint2 u; __builtin_memcpy(&u, &d, 8);
            *(uint2*)&h2S[2 * tid] = u;
        }
        __syncthreads();
        {   // energies
            int tl = tid >> 2, ks = tid & 3;
            float e = 0.f;
            if (tl < tn) {
                const uint4* kr = (const uint4*)&keyL[tl * 68] + ks * 4;
                const uint4* hr = (const uint4*)&h2S[ks * 16];
#pragma unroll
                for (int it = 0; it < 4; ++it) {
                    uint4 kv = kr[it]; uint4 hv = hr[it];
                    e = dot2(kv.x, hv.x, e); e = dot2(kv.y, hv.y, e);
                    e = dot2(kv.z, hv.z, e); e = dot2(kv.w, hv.w, e);
                }
            }
            e += __shfl_xor(e, 1);
            e += __shfl_xor(e, 2);
            if (ks == 0 && tl < tn)
                eS[tl] = (t0 + tl < len_att) ? e : 0.0f;
        }
        __syncthreads();
        float att_m = 0.f, att_s = 0.f;
        {
            float me = -1e30f, p = 0.f;
            if (tid < 128) {
                me = (tid < tn) ? eS[tid] : -1e30f;
                float mv = me;
#pragma unroll
                for (int off = 32; off; off >>= 1) mv = fmaxf(mv, __shfl_xor(mv, off));
                if ((tid & 63) == 0) msS[tid >> 6] = mv;
            }
            __syncthreads();
            float m = fmaxf(msS[0], msS[1]);
            if (tid < 128) {
                p = (tid < tn) ? __expf(me - m) : 0.0f;
                float sv = p;
#pragma unroll
                for (int off = 32; off; off >>= 1) sv += __shfl_xor(sv, off);
                if ((tid & 63) == 0) msS[2 + (tid >> 6)] = sv;
                float pnb = __shfl_xor(p, 1);
                if (!(tid & 1)) sph[tid >> 1] = pk(p, pnb);
            }
            __syncthreads();
            att_m = m;
            att_s = msS[2] + msS[3];
        }
        {   // partial context
            int v = tid >> 2, th = tid & 3;
            float a = 0.f;
            const uint4* vr = (const uint4*)&valL[v * 68] + th * 4;
            const uint4* pr = (const uint4*)&sph[th * 16];
#pragma unroll
            for (int it = 0; it < 4; ++it) {
                uint4 vv = vr[it]; uint4 pv = pr[it];
                a = dot2(vv.x, pv.x, a); a = dot2(vv.y, pv.y, a);
                a = dot2(vv.z, pv.z, a); a = dot2(vv.w, pv.w, a);
            }
            a += __shfl_xor(a, 1);
            a += __shfl_xor(a, 2);
            float an = __shfl_xor(a, 4);
            if (th == 0 && !(v & 1))
                cst32(&wc32[tsl * 4096 + b_att * 64 + (v >> 1)], pk(a, an));
            if (tid == 0) {
                float2 msf = make_float2(att_m, att_s);
                ull v64; __builtin_memcpy(&v64, &msf, 8);
                cst64(&wmsU[tsl * 64 + b_att], v64);
            }
        }
        ++bk; gb_arrive(bar, g, bk);
        gb_wait(bar, g, bk);
    }

    // tail: ctx rows for l = 249
    if (s == 0 && tid < 256) {
        int bl = tid & 3, vp = tid >> 2;
        float cx, cy;
        ctx_merge(wc32, wmsU, 4 * g + bl, vp, &cx, &cy);
        float* hd = &h2ctx[((size_t)(4 * g + bl) * LL + (LL - 1)) * 256 + 128 + 2 * vp];
        hd[0] = cx; hd[1] = cy;
    }
}

// ---------------------------------------------------------------------------
extern "C" void kernel_launch(void* const* d_in, const int* in_sizes, int n_in,
                              void* d_out, int out_size, void* d_ws, size_t ws_size,
                              hipStream_t stream) {
    const float* key        = (const float*)d_in[0];
    const float* values     = (const float*)d_in[1];
    const int*   speech_len = (const int*)d_in[2];
    const int*   text       = (const int*)d_in[3];
    const float* embedding  = (const float*)d_in[4];
    const float* w_ih1 = (const float*)d_in[5];
    const float* b_ih1 = (const float*)d_in[6];
    const float* w_hh1 = (const float*)d_in[7];
    const float* b_hh1 = (const float*)d_in[8];
    const float* w_ih2 = (const float*)d_in[9];
    const float* b_ih2 = (const float*)d_in[10];
    const float* w_hh2 = (const float*)d_in[11];
    const float* b_hh2 = (const float*)d_in[12];
    const float* w_out = (const float*)d_in[13];
    const float* b_out = (const float*)d_in[14];
    float* out = (float*)d_out;

    float* ws    = (float*)d_ws;
    float* h2ctx = ws + WS_H2CTX;

    float* EmbW = out + OUT_EMBW;
    unsigned* EG2u = (unsigned*)(out + OUT_EG);
    unsigned* wp1  = (unsigned*)(out + OUT_WP1);
    unsigned* wp2  = (unsigned*)(out + OUT_WP2);
    unsigned* keyg = (unsigned*)(out + OUT_KEYG);
    unsigned* valg = (unsigned*)(out + OUT_VALG);

    (void)hipFuncSetAttribute((const void*)k_loop,
                              hipFuncAttributeMaxDynamicSharedMemorySize, LDS_BYTES);

    k_init<<<115, 512, 0, stream>>>(values, ws);
    k_pack<<<(PK_TOT + 511) / 512, 512, 0, stream>>>(key, values, w_ih1, w_hh1,
                                                     w_ih2, w_hh2, wp1, wp2, keyg, valg);
    // EmbW[v][j] = embedding[v] . w_ih1[j][:256] + b_ih1[j] + b_hh1[j]
    k_gemm_tn<<<dim3(32, 64), 256, 0, stream>>>(embedding, 256, w_ih1, 384,
                                                b_ih1, b_hh1, EmbW, 2048);
    k_eg2<<<dim3(8, 250), 512, 0, stream>>>(text, EmbW, EG2u);
    k_loop<<<NBLK, 512, LDS_BYTES, stream>>>(speech_len, EG2u, wp1, wp2, keyg, valg,
                                             b_ih2, b_hh2, ws);
    // out[b*250+l][v] = h2ctx[b*250+l] . w_out[v] + b_out[v]
    k_gemm_tn<<<dim3(64, 250), 256, 0, stream>>>(h2ctx, 256, w_out, 256,
                                                 b_out, nullptr, out, 4096);
}

// Round 11
// 4422.636 us; speedup vs baseline: 1.8565x; 1.0629x over previous
//
#include <hip/hip_runtime.h>
#include <hip/hip_fp16.h>

#define LL 250
#define NBLK 256

typedef unsigned long long ull;

// ---- ws u32 offsets ----
#define WS_BAR    0        // 16 groups x 32 u32: cnt @ +0 (monotonic, polled directly)
#define WS_HG     1024     // [2][64 b][256] u32 fp16-pairs of h1
#define WS_H2G    33792    // [2][64 b][64] u32 fp16-pairs of h2
#define WS_WC     41984    // [4 ts][64 b][64 vp] u32 partial ctx
#define WS_WMS    58368    // [4][64][2] f32 (m,s)
#define WS_H2CTX  58880    // [64*250][256] f32
#define WS_INIT_END 58880

// ---- out scratch (float index units) ----
#define OUT_EMBW  0                 // 4096*2048 f32
#define OUT_EG    8388608           // EG2: 250*16*2048*2 u32
#define OUT_WP1   25165824          // 2048*320 u32
#define OUT_WP2   25821184          // 512*320 u32
#define OUT_KEYG  25985024          // 64*500*64 u32
#define OUT_VALG  28033024          // 64*128*250 u32

// ---- k_loop LDS byte offsets ----
#define L_KEY  0                    // [126][68] u32 = 34272
#define L_VAL  34272                // [128][68] u32 = 34816
#define L_X    69088                // [4][328] u32 = 5248
#define L_G    74336                // 512 f32 (S2 partials)
#define L_E    76384                // 128 f32
#define L_SPH  76896                // 64 u32
#define L_MS   77152                // 8 f32
#define L_H2S  77184                // 64 u32
#define L_B2   77440                // 32 f32
#define L_GX   77568                // [2][128][4] f32 = 4096 (S1 partials)
#define LDS_BYTES 81664

__device__ __forceinline__ float sigm(float x) { return 1.0f / (1.0f + __expf(-x)); }

__device__ __forceinline__ unsigned pk(float a, float b) {
    __half2 h;
    h.x = __float2half_rn(a); h.y = __float2half_rn(b);
    unsigned u; __builtin_memcpy(&u, &h, 4); return u;
}
__device__ __forceinline__ float2 upk(unsigned u) {
    __half2 h; __builtin_memcpy(&h, &u, 4);
    return make_float2(__half2float(h.x), __half2float(h.y));
}

// coherent (agent-scope, L2-bypassing) exchange accessors
__device__ __forceinline__ ull cld64(const ull* p) {
    return __hip_atomic_load(p, __ATOMIC_RELAXED, __HIP_MEMORY_SCOPE_AGENT);
}
__device__ __forceinline__ unsigned cld32(const unsigned* p) {
    return __hip_atomic_load(p, __ATOMIC_RELAXED, __HIP_MEMORY_SCOPE_AGENT);
}
__device__ __forceinline__ void cst64(ull* p, ull v) {
    __hip_atomic_store(p, v, __ATOMIC_RELAXED, __HIP_MEMORY_SCOPE_AGENT);
}
__device__ __forceinline__ void cst32(unsigned* p, unsigned v) {
    __hip_atomic_store(p, v, __ATOMIC_RELAXED, __HIP_MEMORY_SCOPE_AGENT);
}

#ifndef __has_builtin
#define __has_builtin(x) 0
#endif
#if __has_builtin(__builtin_amdgcn_fdot2)
typedef _Float16 h2vec __attribute__((ext_vector_type(2)));
__device__ __forceinline__ float dot2(unsigned a, unsigned b, float c) {
    h2vec ha, hb;
    __builtin_memcpy(&ha, &a, 4); __builtin_memcpy(&hb, &b, 4);
    return __builtin_amdgcn_fdot2(ha, hb, c, false);
}
#else
__device__ __forceinline__ float dot2(unsigned a, unsigned b, float c) {
    float2 fa = upk(a), fb = upk(b);
    return c + fa.x * fb.x + fa.y * fb.y;
}
#endif

// ---------------------------------------------------------------------------
__global__ __launch_bounds__(512) void k_init(const float* __restrict__ values,
                                              float* __restrict__ ws) {
    int i = blockIdx.x * 512 + threadIdx.x;
    if (i >= WS_INIT_END) return;
    unsigned* wsu = (unsigned*)ws;
    if (i >= WS_WC && i < WS_WC + 4096) {          // wc[0][bg][vp] = values[t=0]
        int r = i - WS_WC, bg = r >> 6, vp = r & 63;
        wsu[i] = pk(values[bg * 128 + 2 * vp], values[bg * 128 + 2 * vp + 1]);
    } else if (i >= WS_WMS) {
        int r = i - WS_WMS;                        // [4][64][2]: slice0 (m=0,s=1)
        ws[i] = (((r >> 7) == 0) && (r & 1)) ? 1.0f : 0.0f;
    } else {
        ws[i] = 0.0f;
    }
}

// ---------------------------------------------------------------------------
// pack weights/key/values to fp16 pairs
// ---------------------------------------------------------------------------
#define PK_W1 655360
#define PK_W2 819200
#define PK_KEY 2867200
#define PK_TOT 4915200
__global__ __launch_bounds__(512) void k_pack(
        const float* __restrict__ key, const float* __restrict__ values,
        const float* __restrict__ w_ih1, const float* __restrict__ w_hh1,
        const float* __restrict__ w_ih2, const float* __restrict__ w_hh2,
        unsigned* __restrict__ wp1, unsigned* __restrict__ wp2,
        unsigned* __restrict__ keyg, unsigned* __restrict__ valg) {
    int idx = blockIdx.x * 512 + threadIdx.x;
    if (idx >= PK_TOT) return;
    if (idx < PK_W1) {
        int j = idx / 320, kp = idx % 320, k0 = 2 * kp;
        float a, b;
        if (k0 < 128) { a = w_ih1[j * 384 + 256 + k0]; b = w_ih1[j * 384 + 257 + k0]; }
        else          { a = w_hh1[j * 512 + k0 - 128]; b = w_hh1[j * 512 + k0 - 127]; }
        wp1[idx] = pk(a, b);
    } else if (idx < PK_W2) {
        int i2 = idx - PK_W1;
        int j = i2 / 320, kp = i2 % 320, k0 = 2 * kp;
        float a, b;
        if (k0 < 512) { a = w_ih2[j * 512 + k0]; b = w_ih2[j * 512 + k0 + 1]; }
        else          { a = w_hh2[j * 128 + k0 - 512]; b = w_hh2[j * 128 + k0 - 511]; }
        wp2[i2] = pk(a, b);
    } else if (idx < PK_KEY) {
        int i2 = idx - PK_W2;
        int b = i2 / 32000, r = i2 % 32000, t = r >> 6, kp = r & 63;
        const float* kr = key + ((size_t)t * 64 + b) * 128 + 2 * kp;
        keyg[i2] = pk(kr[0], kr[1]);
    } else {
        int i2 = idx - PK_KEY;
        int b = i2 / 32000, r = i2 % 32000, tp = r >> 7, v = r & 127;
        valg[b * 32000 + v * 250 + tp] =
            pk(values[((size_t)(2 * tp) * 64 + b) * 128 + v],
               values[((size_t)(2 * tp + 1) * 64 + b) * 128 + v]);
    }
}

// ---------------------------------------------------------------------------
// EG2[l][g][j] = uint2{ pk(b0,b1), pk(b2,b3) } of EmbW[tok][j]
// ---------------------------------------------------------------------------
__global__ __launch_bounds__(512) void k_eg2(const int* __restrict__ text,
                                             const float* __restrict__ EmbW,
                                             unsigned* __restrict__ EG2u) {
    const int jc = blockIdx.x, l = blockIdx.y;
    const int tid = threadIdx.x;
    __shared__ int tokL[64];
    if (tid < 64) tokL[tid] = (l == 0) ? 0 : text[tid * LL + l - 1];
    __syncthreads();
    const int j = jc * 256 + (tid & 255);
    const int half = tid >> 8;
    for (int gi = 0; gi < 8; ++gi) {
        int g = half * 8 + gi;
        float a0 = EmbW[(size_t)tokL[4 * g + 0] * 2048 + j];
        float a1 = EmbW[(size_t)tokL[4 * g + 1] * 2048 + j];
        float a2 = EmbW[(size_t)tokL[4 * g + 2] * 2048 + j];
        float a3 = EmbW[(size_t)tokL[4 * g + 3] * 2048 + j];
        uint2 u = make_uint2(pk(a0, a1), pk(a2, a3));
        *(uint2*)&EG2u[((size_t)(l * 16 + g) * 2048 + j) * 2] = u;
    }
}

// ---------------------------------------------------------------------------
// fp32 GEMM (K=256) — EmbW precompute and final projection
// ---------------------------------------------------------------------------
__global__ __launch_bounds__(256) void k_gemm_tn(
        const float* __restrict__ A, int lda,
        const float* __restrict__ B, int ldb,
        const float* __restrict__ bias1, const float* __restrict__ bias2,
        float* __restrict__ C, int ldc) {
    const int tid = threadIdx.x;
    const int m0 = blockIdx.y * 64, n0 = blockIdx.x * 64;
    const int tx = tid & 15, ty = tid >> 4;
    const int lm = tid >> 2, lk = (tid & 3) * 8;
    __shared__ float As[32][68];
    __shared__ float Bs[32][68];
    float c[4][4] = {{0.f}};
    for (int kb = 0; kb < 256; kb += 32) {
        const float* ap = A + (size_t)(m0 + lm) * lda + kb + lk;
        const float* bp = B + (size_t)(n0 + lm) * ldb + kb + lk;
        float4 a0 = *(const float4*)(ap);
        float4 a1 = *(const float4*)(ap + 4);
        float4 b0 = *(const float4*)(bp);
        float4 b1 = *(const float4*)(bp + 4);
        __syncthreads();
        As[lk + 0][lm] = a0.x; As[lk + 1][lm] = a0.y; As[lk + 2][lm] = a0.z; As[lk + 3][lm] = a0.w;
        As[lk + 4][lm] = a1.x; As[lk + 5][lm] = a1.y; As[lk + 6][lm] = a1.z; As[lk + 7][lm] = a1.w;
        Bs[lk + 0][lm] = b0.x; Bs[lk + 1][lm] = b0.y; Bs[lk + 2][lm] = b0.z; Bs[lk + 3][lm] = b0.w;
        Bs[lk + 4][lm] = b1.x; Bs[lk + 5][lm] = b1.y; Bs[lk + 6][lm] = b1.z; Bs[lk + 7][lm] = b1.w;
        __syncthreads();
#pragma unroll
        for (int kk = 0; kk < 32; ++kk) {
            const float4 a = *(const float4*)&As[kk][ty * 4];
            const float4 b = *(const float4*)&Bs[kk][tx * 4];
            c[0][0] += a.x * b.x; c[0][1] += a.x * b.y; c[0][2] += a.x * b.z; c[0][3] += a.x * b.w;
            c[1][0] += a.y * b.x; c[1][1] += a.y * b.y; c[1][2] += a.y * b.z; c[1][3] += a.y * b.w;
            c[2][0] += a.z * b.x; c[2][1] += a.z * b.y; c[2][2] += a.z * b.z; c[2][3] += a.z * b.w;
            c[3][0] += a.w * b.x; c[3][1] += a.w * b.y; c[3][2] += a.w * b.z; c[3][3] += a.w * b.w;
        }
    }
    const int n = n0 + tx * 4;
    float4 bb = *(const float4*)&bias1[n];
    if (bias2) {
        float4 b2 = *(const float4*)&bias2[n];
        bb.x += b2.x; bb.y += b2.y; bb.z += b2.z; bb.w += b2.w;
    }
#pragma unroll
    for (int i = 0; i < 4; ++i) {
        float4 r;
        r.x = c[i][0] + bb.x; r.y = c[i][1] + bb.y; r.z = c[i][2] + bb.z; r.w = c[i][3] + bb.w;
        *(float4*)&C[(size_t)(m0 + ty * 4 + i) * ldc + n] = r;
    }
}

// ---------------------------------------------------------------------------
// Counter-based group sync, split arrive/wait. Waiters poll the arrival
// counter DIRECTLY (cnt >= 16*bk) — removes the last-arriver gen-store hop.
// Monotonic; relaxed atomics; arrive's __syncthreads drains vmcnt first.
// ---------------------------------------------------------------------------
__device__ __forceinline__ void gb_arrive(unsigned* bar, int g, unsigned bk) {
    __syncthreads();
    if (threadIdx.x == 0)
        __hip_atomic_fetch_add(bar + g * 32, 1u, __ATOMIC_RELAXED, __HIP_MEMORY_SCOPE_AGENT);
}
__device__ __forceinline__ void gb_wait(unsigned* bar, int g, unsigned bk) {
    if (threadIdx.x == 0) {
        unsigned* cnt = bar + g * 32;
        while (__hip_atomic_load(cnt, __ATOMIC_RELAXED, __HIP_MEMORY_SCOPE_AGENT) < bk * 16u)
            __builtin_amdgcn_s_sleep(1);
    }
    __syncthreads();
}

// exact 4-slice merge: ctx-pair for (bgs, vp)
__device__ __forceinline__ void ctx_merge(const unsigned* __restrict__ wc32,
                                          const ull* __restrict__ wmsU,
                                          int bgs, int vp, float* cx, float* cy) {
    float m[4], sv[4];
#pragma unroll
    for (int q = 0; q < 4; ++q) {
        ull v = cld64(&wmsU[q * 64 + bgs]);
        float2 f; __builtin_memcpy(&f, &v, 8);
        m[q] = f.x; sv[q] = f.y;
    }
    float M = fmaxf(fmaxf(m[0], m[1]), fmaxf(m[2], m[3]));
    float w[4];
    float den = 0.f;
#pragma unroll
    for (int q = 0; q < 4; ++q) { w[q] = __expf(m[q] - M); den += w[q] * sv[q]; }
    float inv = 1.0f / den;
    float x = 0.f, y = 0.f;
#pragma unroll
    for (int q = 0; q < 4; ++q) {
        float2 f = upk(cld32(&wc32[q * 4096 + bgs * 64 + vp]));
        x += w[q] * f.x; y += w[q] * f.y;
    }
    *cx = x * inv; *cy = y * inv;
}

// ---------------------------------------------------------------------------
// Persistent kernel: 16 groups x 16 blocks; group owns 4 batch elems.
// S1 LSTM1 (2 rows/thread, half the LDS reads) | sync | S2 LSTM2 | sync |
// S3 attention slice | sync. Staging pipelined into sync windows:
//   win1: h2-prev -> xL[256..320) + ctx-row write
//   win2: h2ctx h2-row write
//   win3: h1(next step) -> xL[64..320) + EG preload
// ---------------------------------------------------------------------------
__global__ __launch_bounds__(512) void k_loop(
        const int* __restrict__ speech_len,
        const unsigned* __restrict__ EG2u,
        const unsigned* __restrict__ wp1, const unsigned* __restrict__ wp2,
        const unsigned* __restrict__ keyg, const unsigned* __restrict__ valg,
        const float* __restrict__ b_ih2, const float* __restrict__ b_hh2,
        float* __restrict__ ws) {
    extern __shared__ char smem[];
    const int blk = blockIdx.x;
    const int tid = threadIdx.x;
    const int g = blk >> 4, s = blk & 15;

    unsigned* wsu = (unsigned*)ws;
    unsigned* bar   = wsu + WS_BAR;
    ull*      hgU   = (ull*)(wsu + WS_HG);     // [2][64][128]
    unsigned* hg32  = wsu + WS_HG;             // [2][64][256]
    ull*      h2gU  = (ull*)(wsu + WS_H2G);    // [2][64][32]
    unsigned* h2g32 = wsu + WS_H2G;            // [2][64][64]
    unsigned* wc32  = wsu + WS_WC;             // [4][64][64]
    ull*      wmsU  = (ull*)(wsu + WS_WMS);    // [4][64]
    float*    h2ctx = ws + WS_H2CTX;

    unsigned* keyL = (unsigned*)(smem + L_KEY);   // [126][68]
    unsigned* valL = (unsigned*)(smem + L_VAL);   // [128][68]
    unsigned* xL   = (unsigned*)(smem + L_X);     // [4][328]
    float*    gS   = (float*)(smem + L_G);        // [512]  (S2)
    float*    eS   = (float*)(smem + L_E);        // [128]
    unsigned* sph  = (unsigned*)(smem + L_SPH);   // [64]
    float*    msS  = (float*)(smem + L_MS);       // [8]
    unsigned* h2S  = (unsigned*)(smem + L_H2S);   // [64]
    float*    b2S  = (float*)(smem + L_B2);       // [32]
    float*    gSx  = (float*)(smem + L_GX);       // [2][128][4] (S1)

    // attention slice geometry
    const int bl_att = s & 3, tsl = s >> 2;
    const int b_att = 4 * g + bl_att;
    const int pn  = (tsl < 2) ? 63 : 62;
    const int pp0 = (tsl < 2) ? 63 * tsl : 126 + 62 * (tsl - 2);
    const int t0 = 2 * pp0, tn = 2 * pn;

    // S1 gate-thread geometry (2 rows per thread, k-halved)
    const int kh1 = tid >> 8;              // 0,1
    const int rp1 = (tid >> 2) & 63;       // 0..63
    const int bl1 = tid & 3;
    const int ra = 2 * rp1, rb = ra + 1;
    const int ja = (ra >> 5) * 512 + s * 32 + (ra & 31);
    const int jb = (rb >> 5) * 512 + s * 32 + (rb & 31);
    const int gxa = (ra >> 5) * 128 + (ra & 31) * 4 + bl1;   // gSx idx row a

    // ---- prologue: key/val slices to LDS, lstm2 bias ----
    for (int i = tid; i < tn * 64; i += 512) {
        int tl = i >> 6, kp = i & 63;
        keyL[tl * 68 + kp] = keyg[(size_t)b_att * 32000 + (size_t)(t0 + tl) * 64 + kp];
    }
    for (int i = tid; i < 128 * 64; i += 512) {
        int v = i >> 6, pp = i & 63;
        valL[v * 68 + pp] = (pp < pn)
            ? valg[(size_t)b_att * 32000 + v * 250 + pp0 + pp] : 0u;
    }
    if (tid < 32) {
        int j2 = (tid >> 3) * 128 + s * 8 + (tid & 7);
        b2S[tid] = b_ih2[j2] + b_hh2[j2];
    }
    const int len_att = speech_len[b_att];

    // ---- preamble staging for l=0: h1(zeros) -> xL[64..320), EG preload ----
    {
        int bl = tid >> 7, qp = tid & 127;
        ull d = cld64(&hgU[(size_t)0 * 8192 + (4 * g + bl) * 128 + qp]);
        uint2 u; __builtin_memcpy(&u, &d, 8);
        *(uint2*)&xL[bl * 328 + 64 + 2 * qp] = u;
    }
    float egA = 0.f, egB = 0.f;
    if (kh1 == 0) {
        float2 ea = upk(EG2u[((size_t)(0 * 16 + g) * 2048 + ja) * 2 + (bl1 >> 1)]);
        egA = (bl1 & 1) ? ea.y : ea.x;
        float2 eb = upk(EG2u[((size_t)(0 * 16 + g) * 2048 + jb) * 2 + (bl1 >> 1)]);
        egB = (bl1 & 1) ? eb.y : eb.x;
    }
    __syncthreads();

    float c1 = 0.f, c2 = 0.f;
    unsigned bk = 0;

    for (int l = 0; l < LL; ++l) {
        const int cur = l & 1, nxt = cur ^ 1;
        float ctx_cx = 0.f, ctx_cy = 0.f;
        float h2_save = 0.f;

        // ================= S1: LSTM1 =================
        if (tid < 256) {  // ctx merge into xL[bl][0..64); keep for tail write
            int bl = tid & 3, vp = tid >> 2;
            ctx_merge(wc32, wmsU, 4 * g + bl, vp, &ctx_cx, &ctx_cy);
            xL[bl * 328 + vp] = pk(ctx_cx, ctx_cy);
        }
        __syncthreads();
        {   // gates: 2 rows per thread, k-half split, 1 LDS read feeds 8 dot2
            float aa0 = 0.f, aa1 = 0.f, ab0 = 0.f, ab1 = 0.f;
            const uint4* wpa = (const uint4*)(wp1 + (size_t)ja * 320) + kh1 * 40;
            const uint4* wpb = (const uint4*)(wp1 + (size_t)jb * 320) + kh1 * 40;
            const unsigned* xb = &xL[bl1 * 328 + kh1 * 160];
#pragma unroll 8
            for (int it = 0; it < 40; ++it) {
                uint4 xv = *(const uint4*)&xb[it * 4];
                uint4 wa = wpa[it];
                uint4 wb = wpb[it];
                aa0 = dot2(wa.x, xv.x, aa0); aa1 = dot2(wa.y, xv.y, aa1);
                aa0 = dot2(wa.z, xv.z, aa0); aa1 = dot2(wa.w, xv.w, aa1);
                ab0 = dot2(wb.x, xv.x, ab0); ab1 = dot2(wb.y, xv.y, ab1);
                ab0 = dot2(wb.z, xv.z, ab0); ab1 = dot2(wb.w, xv.w, ab1);
            }
            float sa = aa0 + aa1, sb = ab0 + ab1;
            if (kh1 == 0) { sa += egA; sb += egB; }
            gSx[kh1 * 512 + gxa] = sa;
            gSx[kh1 * 512 + gxa + 4] = sb;
        }
        __syncthreads();
        if (tid < 128) {
            int hl = tid >> 2, bl = tid & 3;
            float g0 = gSx[hl * 4 + bl]       + gSx[512 + hl * 4 + bl];
            float g1 = gSx[128 + hl * 4 + bl] + gSx[640 + hl * 4 + bl];
            float g2 = gSx[256 + hl * 4 + bl] + gSx[768 + hl * 4 + bl];
            float g3 = gSx[384 + hl * 4 + bl] + gSx[896 + hl * 4 + bl];
            float iv = sigm(g0), fv = sigm(g1), gv = tanhf(g2), ov = sigm(g3);
            c1 = fv * c1 + iv * gv;
            float h1v = ov * tanhf(c1);
            float hp = __shfl_xor(h1v, 4);
            if (!(hl & 1))
                cst32(&hg32[nxt * 16384 + (4 * g + bl) * 256 + s * 16 + (hl >> 1)],
                      pk(h1v, hp));
        }
        ++bk; gb_arrive(bar, g, bk);
        // ---- window 1: ctx-row write + h2-prev staging (both pre-synced data) ----
        if (s == 0 && l > 0 && tid < 256) {
            int bl = tid & 3, vp = tid >> 2;
            float* hd = &h2ctx[((size_t)(4 * g + bl) * LL + (l - 1)) * 256 + 128 + 2 * vp];
            hd[0] = ctx_cx; hd[1] = ctx_cy;
        }
        if (tid < 128) {  // h2(l-1) -> xL[bl][256..320)
            int bl = tid >> 5, qp = tid & 31;
            ull d = cld64(&h2gU[(size_t)cur * 2048 + (4 * g + bl) * 32 + qp]);
            uint2 u; __builtin_memcpy(&u, &d, 8);
            *(uint2*)&xL[bl * 328 + 256 + 2 * qp] = u;
        }
        gb_wait(bar, g, bk);

        // ================= S2: LSTM2 =================
        {   // stage full h1 into xL[bl][0..256) (just produced, post-wait)
            int bl = tid >> 7, qp = tid & 127;
            ull d = cld64(&hgU[(size_t)nxt * 8192 + (4 * g + bl) * 128 + qp]);
            uint2 u; __builtin_memcpy(&u, &d, 8);
            *(uint2*)&xL[bl * 328 + 2 * qp] = u;
        }
        __syncthreads();
        {
            int job = tid >> 2, ks = tid & 3;
            int rl2 = job >> 2, bl = job & 3;
            int j2 = (rl2 >> 3) * 128 + s * 8 + (rl2 & 7);
            float acc0 = (ks == 0) ? b2S[rl2] : 0.f;
            float acc1 = 0.f;
            const uint4* wp = (const uint4*)(wp2 + (size_t)j2 * 320) + ks * 20;
            const unsigned* xb = &xL[bl * 328 + ks * 80];
#pragma unroll 5
            for (int it = 0; it < 20; ++it) {
                uint4 wv = wp[it];
                uint4 xv = *(const uint4*)&xb[it * 4];
                acc0 = dot2(wv.x, xv.x, acc0); acc1 = dot2(wv.y, xv.y, acc1);
                acc0 = dot2(wv.z, xv.z, acc0); acc1 = dot2(wv.w, xv.w, acc1);
            }
            float acc = acc0 + acc1;
            acc += __shfl_xor(acc, 1);
            acc += __shfl_xor(acc, 2);
            if (ks == 0) gS[job] = acc;
        }
        __syncthreads();
        if (tid < 32) {
            int rl = tid >> 2, bl = tid & 3;
            float g0 = gS[tid], g1 = gS[32 + tid], g2 = gS[64 + tid], g3 = gS[96 + tid];
            float iv = sigm(g0), fv = sigm(g1), gv = tanhf(g2), ov = sigm(g3);
            c2 = fv * c2 + iv * gv;
            float h2v = ov * tanhf(c2);
            h2_save = h2v;
            float hp = __shfl_xor(h2v, 4);
            if (!(rl & 1))
                cst32(&h2g32[nxt * 4096 + (4 * g + bl) * 64 + s * 4 + (rl >> 1)],
                      pk(h2v, hp));
        }
        ++bk; gb_arrive(bar, g, bk);
        if (tid < 32) {                          // window 2: h2ctx h2 row
            int rl = tid >> 2, bl = tid & 3;
            h2ctx[((size_t)(4 * g + bl) * LL + l) * 256 + s * 8 + rl] = h2_save;
        }
        gb_wait(bar, g, bk);

        // ================= S3: attention slice =================
        if (tid < 32) {
            ull d = cld64(&h2gU[(size_t)nxt * 2048 + b_att * 32 + tid]);
            uint2 u; __builtin_memcpy(&u, &d, 8);
            *(uint2*)&h2S[2 * tid] = u;
        }
        __syncthreads();
        {   // energies
            int tl = tid >> 2, ks = tid & 3;
            float e = 0.f;
            if (tl < tn) {
                const uint4* kr = (const uint4*)&keyL[tl * 68] + ks * 4;
                const uint4* hr = (const uint4*)&h2S[ks * 16];
#pragma unroll
                for (int it = 0; it < 4; ++it) {
                    uint4 kv = kr[it]; uint4 hv = hr[it];
                    e = dot2(kv.x, hv.x, e); e = dot2(kv.y, hv.y, e);
                    e = dot2(kv.z, hv.z, e); e = dot2(kv.w, hv.w, e);
                }
            }
            e += __shfl_xor(e, 1);
            e += __shfl_xor(e, 2);
            if (ks == 0 && tl < tn)
                eS[tl] = (t0 + tl < len_att) ? e : 0.0f;
        }
        __syncthreads();
        float att_m = 0.f, att_s = 0.f;
        {
            float me = -1e30f, p = 0.f;
            if (tid < 128) {
                me = (tid < tn) ? eS[tid] : -1e30f;
                float mv = me;
#pragma unroll
                for (int off = 32; off; off >>= 1) mv = fmaxf(mv, __shfl_xor(mv, off));
                if ((tid & 63) == 0) msS[tid >> 6] = mv;
            }
            __syncthreads();
            float m = fmaxf(msS[0], msS[1]);
            if (tid < 128) {
                p = (tid < tn) ? __expf(me - m) : 0.0f;
                float sv = p;
#pragma unroll
                for (int off = 32; off; off >>= 1) sv += __shfl_xor(sv, off);
                if ((tid & 63) == 0) msS[2 + (tid >> 6)] = sv;
                float pnb = __shfl_xor(p, 1);
                if (!(tid & 1)) sph[tid >> 1] = pk(p, pnb);
            }
            __syncthreads();
            att_m = m;
            att_s = msS[2] + msS[3];
        }
        {   // partial context
            int v = tid >> 2, th = tid & 3;
            float a = 0.f;
            const uint4* vr = (const uint4*)&valL[v * 68] + th * 4;
            const uint4* pr = (const uint4*)&sph[th * 16];
#pragma unroll
            for (int it = 0; it < 4; ++it) {
                uint4 vv = vr[it]; uint4 pv = pr[it];
                a = dot2(vv.x, pv.x, a); a = dot2(vv.y, pv.y, a);
                a = dot2(vv.z, pv.z, a); a = dot2(vv.w, pv.w, a);
            }
            a += __shfl_xor(a, 1);
            a += __shfl_xor(a, 2);
            float an = __shfl_xor(a, 4);
            if (th == 0 && !(v & 1))
                cst32(&wc32[tsl * 4096 + b_att * 64 + (v >> 1)], pk(a, an));
            if (tid == 0) {
                float2 msf = make_float2(att_m, att_s);
                ull v64; __builtin_memcpy(&v64, &msf, 8);
                cst64(&wmsU[tsl * 64 + b_att], v64);
            }
        }
        ++bk; gb_arrive(bar, g, bk);
        // ---- window 3: stage h1 for step l+1 + EG preload (pre-synced data) ----
        {
            int bl = tid >> 7, qp = tid & 127;
            ull d = cld64(&hgU[(size_t)nxt * 8192 + (4 * g + bl) * 128 + qp]);
            uint2 u; __builtin_memcpy(&u, &d, 8);
            *(uint2*)&xL[bl * 328 + 64 + 2 * qp] = u;
        }
        if (kh1 == 0 && l + 1 < LL) {
            float2 ea = upk(EG2u[((size_t)((l + 1) * 16 + g) * 2048 + ja) * 2 + (bl1 >> 1)]);
            egA = (bl1 & 1) ? ea.y : ea.x;
            float2 eb = upk(EG2u[((size_t)((l + 1) * 16 + g) * 2048 + jb) * 2 + (bl1 >> 1)]);
            egB = (bl1 & 1) ? eb.y : eb.x;
        }
        gb_wait(bar, g, bk);
    }

    // tail: ctx rows for l = 249
    if (s == 0 && tid < 256) {
        int bl = tid & 3, vp = tid >> 2;
        float cx, cy;
        ctx_merge(wc32, wmsU, 4 * g + bl, vp, &cx, &cy);
        float* hd = &h2ctx[((size_t)(4 * g + bl) * LL + (LL - 1)) * 256 + 128 + 2 * vp];
        hd[0] = cx; hd[1] = cy;
    }
}

// ---------------------------------------------------------------------------
extern "C" void kernel_launch(void* const* d_in, const int* in_sizes, int n_in,
                              void* d_out, int out_size, void* d_ws, size_t ws_size,
                              hipStream_t stream) {
    const float* key        = (const float*)d_in[0];
    const float* values     = (const float*)d_in[1];
    const int*   speech_len = (const int*)d_in[2];
    const int*   text       = (const int*)d_in[3];
    const float* embedding  = (const float*)d_in[4];
    const float* w_ih1 = (const float*)d_in[5];
    const float* b_ih1 = (const float*)d_in[6];
    const float* w_hh1 = (const float*)d_in[7];
    const float* b_hh1 = (const float*)d_in[8];
    const float* w_ih2 = (const float*)d_in[9];
    const float* b_ih2 = (const float*)d_in[10];
    const float* w_hh2 = (const float*)d_in[11];
    const float* b_hh2 = (const float*)d_in[12];
    const float* w_out = (const float*)d_in[13];
    const float* b_out = (const float*)d_in[14];
    float* out = (float*)d_out;

    float* ws    = (float*)d_ws;
    float* h2ctx = ws + WS_H2CTX;

    float* EmbW = out + OUT_EMBW;
    unsigned* EG2u = (unsigned*)(out + OUT_EG);
    unsigned* wp1  = (unsigned*)(out + OUT_WP1);
    unsigned* wp2  = (unsigned*)(out + OUT_WP2);
    unsigned* keyg = (unsigned*)(out + OUT_KEYG);
    unsigned* valg = (unsigned*)(out + OUT_VALG);

    (void)hipFuncSetAttribute((const void*)k_loop,
                              hipFuncAttributeMaxDynamicSharedMemorySize, LDS_BYTES);

    k_init<<<115, 512, 0, stream>>>(values, ws);
    k_pack<<<(PK_TOT + 511) / 512, 512, 0, stream>>>(key, values, w_ih1, w_hh1,
                                                     w_ih2, w_hh2, wp1, wp2, keyg, valg);
    // EmbW[v][j] = embedding[v] . w_ih1[j][:256] + b_ih1[j] + b_hh1[j]
    k_gemm_tn<<<dim3(32, 64), 256, 0, stream>>>(embedding, 256, w_ih1, 384,
                                                b_ih1, b_hh1, EmbW, 2048);
    k_eg2<<<dim3(8, 250), 512, 0, stream>>>(text, EmbW, EG2u);
    k_loop<<<NBLK, 512, LDS_BYTES, stream>>>(speech_len, EG2u, wp1, wp2, keyg, valg,
                                             b_ih2, b_hh2, ws);
    // out[b*250+l][v] = h2ctx[b*250+l] . w_out[v] + b_out[v]
    k_gemm_tn<<<dim3(64, 250), 256, 0, stream>>>(h2ctx, 256, w_out, 256,
                                                 b_out, nullptr, out, 4096);
}